// Round 1
// baseline (1448.344 us; speedup 1.0000x reference)
//
#include <hip/hip_runtime.h>
#include <stdint.h>

#define B_TOK 32768
#define DM 1024
#define NEXP 16
#define RK 64

typedef unsigned short u16;
typedef __bf16 bf16x8 __attribute__((ext_vector_type(8)));
typedef float f32x4 __attribute__((ext_vector_type(4)));

__device__ __forceinline__ u16 f2bf(float f) {
  union { float f; uint32_t u; } v; v.f = f;
  return (u16)((v.u + 0x7fffu + ((v.u >> 16) & 1u)) >> 16);
}

__device__ __forceinline__ void gload_lds16(const void* g, void* l) {
  __builtin_amdgcn_global_load_lds(
      (const __attribute__((address_space(1))) void*)g,
      (__attribute__((address_space(3))) void*)l, 16, 0, 0);
}

// ---------------- f32 -> bf16 conversion ----------------
__global__ void k_convert(const float* __restrict__ src, u16* __restrict__ dst, int n4) {
  int i = blockIdx.x * blockDim.x + threadIdx.x;
  int stride = gridDim.x * blockDim.x;
  for (; i < n4; i += stride) {
    float4 v = reinterpret_cast<const float4*>(src)[i];
    ushort4 o;
    o.x = f2bf(v.x); o.y = f2bf(v.y); o.z = f2bf(v.z); o.w = f2bf(v.w);
    reinterpret_cast<ushort4*>(dst)[i] = o;
  }
}

// ---------------- fused gating matrix: Wg_eff = Wg @ We, gbias = Wg @ be ----------------
__global__ void k_wgeff(const float* __restrict__ Wg, const float* __restrict__ We,
                        const float* __restrict__ be,
                        float* __restrict__ Wgeff, float* __restrict__ gbias) {
  int e = blockIdx.y;
  int d = blockIdx.x * 256 + threadIdx.x;
  double acc = 0.0;
  for (int k = 0; k < DM; ++k)
    acc += (double)Wg[e * DM + k] * (double)We[k * DM + d];
  Wgeff[e * DM + d] = (float)acc;
  if (blockIdx.x == 0 && threadIdx.x == 0) {
    double s = 0.0;
    for (int k = 0; k < DM; ++k) s += (double)be[k] * (double)Wg[e * DM + k];
    gbias[e] = (float)s;
  }
}

// ---------------- gating: logits = x @ Wg_eff^T (f64 acc), top-2, softmax ----------------
__global__ __launch_bounds__(256) void k_gating(
    const float* __restrict__ x, const float* __restrict__ Wgeff,
    const float* __restrict__ gbias, const float* __restrict__ gamma,
    int* __restrict__ tk_idx, float* __restrict__ tk_w, int* __restrict__ counts) {
  int tok = blockIdx.x;
  int tid = threadIdx.x;
  int e = tid >> 4, c = tid & 15;
  const float* xr = x + (size_t)tok * DM;
  const float* wr = Wgeff + (size_t)e * DM;
  double acc = 0.0;
  #pragma unroll 8
  for (int j = 0; j < 64; ++j) {
    int d = c + 16 * j;
    acc += (double)xr[d] * (double)wr[d];
  }
  __shared__ double red[16][17];
  red[e][c] = acc;
  __syncthreads();
  __shared__ float lg[16];
  if (tid < 16) {
    double s = 0.0;
    for (int cc = 0; cc < 16; ++cc) s += red[tid][cc];
    lg[tid] = (float)s + gbias[tid];  // TAU = 1.0
  }
  __syncthreads();
  if (tid == 0) {
    float v0 = lg[0]; int i0 = 0;
    for (int j = 1; j < NEXP; ++j) if (lg[j] > v0) { v0 = lg[j]; i0 = j; }
    float v1 = -3.4e38f; int i1 = 0;
    for (int j = 0; j < NEXP; ++j) {
      if (j == i0) continue;
      if (lg[j] > v1) { v1 = lg[j]; i1 = j; }
    }
    float e1 = expf(v1 - v0);
    float denom = 1.0f + e1 + 1e-12f;
    float w0 = 1.0f / denom, w1 = e1 / denom;
    if (!(w0 > 1e-12f)) w0 = 0.0f;
    if (!(w1 > 1e-12f)) w1 = 0.0f;
    tk_idx[tok * 2 + 0] = i0;
    tk_idx[tok * 2 + 1] = i1;
    tk_w[tok * 2 + 0] = w0 * gamma[i0];
    tk_w[tok * 2 + 1] = w1 * gamma[i1];
    atomicAdd(&counts[i0], 1);
    atomicAdd(&counts[i1], 1);
  }
}

// ---------------- prefix-scan (16 entries) ----------------
__global__ void k_scan(const int* __restrict__ counts, int* __restrict__ offsets,
                       int* __restrict__ cursors) {
  if (threadIdx.x == 0 && blockIdx.x == 0) {
    int s = 0;
    for (int e = 0; e < NEXP; ++e) { offsets[e] = s; cursors[e] = s; s += counts[e]; }
    offsets[NEXP] = s;
  }
}

// ---------------- scatter token assignments into per-expert lists ----------------
__global__ void k_scatter(const int* __restrict__ tk_idx, const float* __restrict__ tk_w,
                          int* __restrict__ cursors, int* __restrict__ a_tok,
                          float* __restrict__ a_w) {
  int tok = blockIdx.x * blockDim.x + threadIdx.x;
  if (tok >= B_TOK) return;
  #pragma unroll
  for (int k = 0; k < 2; ++k) {
    int e = tk_idx[tok * 2 + k];
    int pos = atomicAdd(&cursors[e], 1);
    a_tok[pos] = tok;
    a_w[pos] = tk_w[tok * 2 + k];
  }
}

// ---------------- encoder GEMM: enc = x @ We^T + be (bf16 MFMA, m97 structure) ----------------
// A = x_bf [M,K] row-major, B = We_bf [N,K] row-major (both K contiguous: "BT" gemm)
__global__ __launch_bounds__(256) void k_encoder(
    const u16* __restrict__ A, const u16* __restrict__ Bm,
    const float* __restrict__ bias, float* __restrict__ Cf, u16* __restrict__ Cb) {
  __shared__ __align__(16) u16 As[128 * 32];
  __shared__ __align__(16) u16 Bs[128 * 32];
  const int m0 = blockIdx.y * 128, n0 = blockIdx.x * 128;
  const int tid = threadIdx.x;
  const int lane = tid & 63, wave = tid >> 6;
  const int wr = wave >> 1, wc = wave & 1;

  f32x4 acc[4][4];
  #pragma unroll
  for (int i = 0; i < 4; ++i)
    #pragma unroll
    for (int j = 0; j < 4; ++j) acc[i][j] = (f32x4){0.f, 0.f, 0.f, 0.f};

  const int srow = tid >> 2;       // 0..63
  const int scol = (tid & 3) * 8;  // bf16 element offset within BK=32
  const int lrow = lane & 15, lk = (lane >> 4) * 8;

  const u16* ga1 = A + (size_t)(m0 + srow) * DM + scol;
  const u16* ga2 = A + (size_t)(m0 + 64 + srow) * DM + scol;
  const u16* gb1 = Bm + (size_t)(n0 + srow) * DM + scol;
  const u16* gb2 = Bm + (size_t)(n0 + 64 + srow) * DM + scol;

  for (int k0 = 0; k0 < DM; k0 += 32) {
    __syncthreads();
    gload_lds16(ga1 + k0, As + srow * 32 + scol);
    gload_lds16(ga2 + k0, As + (64 + srow) * 32 + scol);
    gload_lds16(gb1 + k0, Bs + srow * 32 + scol);
    gload_lds16(gb2 + k0, Bs + (64 + srow) * 32 + scol);
    __syncthreads();
    bf16x8 a[4], b[4];
    #pragma unroll
    for (int mi = 0; mi < 4; ++mi)
      a[mi] = *reinterpret_cast<const bf16x8*>(&As[(wr * 64 + mi * 16 + lrow) * 32 + lk]);
    #pragma unroll
    for (int nj = 0; nj < 4; ++nj)
      b[nj] = *reinterpret_cast<const bf16x8*>(&Bs[(wc * 64 + nj * 16 + lrow) * 32 + lk]);
    #pragma unroll
    for (int mi = 0; mi < 4; ++mi)
      #pragma unroll
      for (int nj = 0; nj < 4; ++nj)
        acc[mi][nj] = __builtin_amdgcn_mfma_f32_16x16x32_bf16(a[mi], b[nj], acc[mi][nj], 0, 0, 0);
  }

  const int orow = (lane >> 4) * 4, ocol = lane & 15;
  #pragma unroll
  for (int mi = 0; mi < 4; ++mi) {
    #pragma unroll
    for (int nj = 0; nj < 4; ++nj) {
      int gcol = n0 + wc * 64 + nj * 16 + ocol;
      float bv = bias[gcol];
      #pragma unroll
      for (int r = 0; r < 4; ++r) {
        int grow = m0 + wr * 64 + mi * 16 + orow + r;
        float v = acc[mi][nj][r] + bv;
        Cf[(size_t)grow * DM + gcol] = v;
        Cb[(size_t)grow * DM + gcol] = f2bf(v);
      }
    }
  }
}

// ---------------- grouped expert kernel: per 64-assignment tile of one expert ----------------
// stage1: H = silu(Enc_g @ U_e^T)  [64 x 64], K=1024
// stage2: Out[tok] += w * (H @ V_e^T)  [64 x 1024], K=64
__global__ __launch_bounds__(256) void k_expert(
    const u16* __restrict__ Enc, const u16* __restrict__ Ub,
    const u16* __restrict__ Vb, const int* __restrict__ offsets,
    const int* __restrict__ a_tok, const float* __restrict__ a_w,
    float* __restrict__ Out) {
  const int e = blockIdx.y;
  const int base = offsets[e];
  const int cnt = offsets[e + 1] - base;
  const int t0 = blockIdx.x * 64;
  if (t0 >= cnt) return;
  const int tid = threadIdx.x;
  const int lane = tid & 63, wave = tid >> 6;

  __shared__ int s_tok[64];
  __shared__ float s_w[64];
  if (tid < 64) {
    int idx = t0 + tid;
    if (idx < cnt) { s_tok[tid] = a_tok[base + idx]; s_w[tid] = a_w[base + idx]; }
    else           { s_tok[tid] = a_tok[base];       s_w[tid] = 0.0f; }
  }
  __shared__ __align__(16) u16 As[64 * 32];
  __shared__ __align__(16) u16 Bs[64 * 32];
  __shared__ __align__(16) u16 Hs[64 * 72];  // padded stride 72 (bank-conflict dodge)
  __syncthreads();

  const int srow = tid >> 2, scol = (tid & 3) * 8;
  const int lrow = lane & 15, lk = (lane >> 4) * 8;
  const int wr = wave >> 1, wc = wave & 1;
  const u16* Ue = Ub + (size_t)e * RK * DM;
  const u16* Ve = Vb + (size_t)e * DM * RK;

  const u16* encRow = Enc + (size_t)s_tok[srow] * DM + scol;
  const u16* uRow = Ue + (size_t)srow * DM + scol;

  f32x4 acc1[2][2];
  #pragma unroll
  for (int i = 0; i < 2; ++i)
    #pragma unroll
    for (int j = 0; j < 2; ++j) acc1[i][j] = (f32x4){0.f, 0.f, 0.f, 0.f};

  for (int k0 = 0; k0 < DM; k0 += 32) {
    __syncthreads();
    gload_lds16(encRow + k0, As + srow * 32 + scol);
    gload_lds16(uRow + k0, Bs + srow * 32 + scol);
    __syncthreads();
    bf16x8 a0 = *reinterpret_cast<const bf16x8*>(&As[(wr * 32 + lrow) * 32 + lk]);
    bf16x8 a1 = *reinterpret_cast<const bf16x8*>(&As[(wr * 32 + 16 + lrow) * 32 + lk]);
    bf16x8 b0 = *reinterpret_cast<const bf16x8*>(&Bs[(wc * 32 + lrow) * 32 + lk]);
    bf16x8 b1 = *reinterpret_cast<const bf16x8*>(&Bs[(wc * 32 + 16 + lrow) * 32 + lk]);
    acc1[0][0] = __builtin_amdgcn_mfma_f32_16x16x32_bf16(a0, b0, acc1[0][0], 0, 0, 0);
    acc1[0][1] = __builtin_amdgcn_mfma_f32_16x16x32_bf16(a0, b1, acc1[0][1], 0, 0, 0);
    acc1[1][0] = __builtin_amdgcn_mfma_f32_16x16x32_bf16(a1, b0, acc1[1][0], 0, 0, 0);
    acc1[1][1] = __builtin_amdgcn_mfma_f32_16x16x32_bf16(a1, b1, acc1[1][1], 0, 0, 0);
  }

  // silu -> Hs (bf16)
  #pragma unroll
  for (int mi = 0; mi < 2; ++mi)
    #pragma unroll
    for (int nj = 0; nj < 2; ++nj)
      #pragma unroll
      for (int r = 0; r < 4; ++r) {
        int trow = wr * 32 + mi * 16 + (lane >> 4) * 4 + r;
        int rcol = wc * 32 + nj * 16 + (lane & 15);
        float z = acc1[mi][nj][r];
        float h = z / (1.0f + expf(-z));
        Hs[trow * 72 + rcol] = f2bf(h);
      }
  __syncthreads();

  // stage 2: each wave owns a 64-wide d-chunk per iteration
  for (int p = 0; p < 4; ++p) {
    int col0 = p * 256 + wave * 64;
    f32x4 acc2[4][4];
    #pragma unroll
    for (int i = 0; i < 4; ++i)
      #pragma unroll
      for (int j = 0; j < 4; ++j) acc2[i][j] = (f32x4){0.f, 0.f, 0.f, 0.f};
    #pragma unroll
    for (int kk = 0; kk < 2; ++kk) {
      bf16x8 hfrag[4];
      #pragma unroll
      for (int mi = 0; mi < 4; ++mi)
        hfrag[mi] = *reinterpret_cast<const bf16x8*>(&Hs[(mi * 16 + lrow) * 72 + kk * 32 + lk]);
      #pragma unroll
      for (int nj = 0; nj < 4; ++nj) {
        int drow = col0 + nj * 16 + lrow;
        bf16x8 vfrag = *reinterpret_cast<const bf16x8*>(&Ve[(size_t)drow * RK + kk * 32 + lk]);
        #pragma unroll
        for (int mi = 0; mi < 4; ++mi)
          acc2[mi][nj] = __builtin_amdgcn_mfma_f32_16x16x32_bf16(hfrag[mi], vfrag, acc2[mi][nj], 0, 0, 0);
      }
    }
    #pragma unroll
    for (int mi = 0; mi < 4; ++mi)
      #pragma unroll
      for (int nj = 0; nj < 4; ++nj)
        #pragma unroll
        for (int r = 0; r < 4; ++r) {
          int trow = mi * 16 + (lane >> 4) * 4 + r;
          int d = col0 + nj * 16 + (lane & 15);
          float v = acc2[mi][nj][r] * s_w[trow];
          if (v != 0.0f) atomicAdd(&Out[(size_t)s_tok[trow] * DM + d], v);
        }
  }
}

// ---------------- host launch ----------------
extern "C" void kernel_launch(void* const* d_in, const int* in_sizes, int n_in,
                              void* d_out, int out_size, void* d_ws, size_t ws_size,
                              hipStream_t stream) {
  const float* x = (const float*)d_in[0];
  const float* We = (const float*)d_in[1];
  const float* be = (const float*)d_in[2];
  const float* Wg = (const float*)d_in[3];
  const float* U = (const float*)d_in[4];
  const float* V = (const float*)d_in[5];
  const float* gamma = (const float*)d_in[6];
  float* Out = (float*)d_out;

  char* ws = (char*)d_ws;
  size_t off = 0;
  auto alloc = [&](size_t bytes) -> void* {
    void* p = ws + off;
    off += (bytes + 255) & ~(size_t)255;
    return p;
  };
  u16* x_bf   = (u16*)alloc((size_t)B_TOK * DM * 2);
  u16* enc_bf = (u16*)alloc((size_t)B_TOK * DM * 2);
  u16* We_bf  = (u16*)alloc((size_t)DM * DM * 2);
  u16* U_bf   = (u16*)alloc((size_t)NEXP * RK * DM * 2);
  u16* V_bf   = (u16*)alloc((size_t)NEXP * DM * RK * 2);
  float* Wgeff = (float*)alloc((size_t)NEXP * DM * 4);
  float* gbias = (float*)alloc(NEXP * 4);
  int* tk_idx  = (int*)alloc((size_t)B_TOK * 2 * 4);
  float* tk_w  = (float*)alloc((size_t)B_TOK * 2 * 4);
  int* counts  = (int*)alloc(NEXP * 4);
  int* offsets = (int*)alloc((NEXP + 1) * 4);
  int* cursors = (int*)alloc(NEXP * 4);
  int* a_tok   = (int*)alloc((size_t)B_TOK * 2 * 4);
  float* a_w   = (float*)alloc((size_t)B_TOK * 2 * 4);
  (void)ws_size; (void)in_sizes; (void)n_in; (void)out_size;

  hipMemsetAsync(counts, 0, NEXP * 4, stream);

  k_convert<<<2048, 256, 0, stream>>>(x, x_bf, B_TOK * DM / 4);
  k_convert<<<256, 256, 0, stream>>>(We, We_bf, DM * DM / 4);
  k_convert<<<256, 256, 0, stream>>>(U, U_bf, NEXP * RK * DM / 4);
  k_convert<<<256, 256, 0, stream>>>(V, V_bf, NEXP * DM * RK / 4);
  k_wgeff<<<dim3(4, 16), 256, 0, stream>>>(Wg, We, be, Wgeff, gbias);
  k_gating<<<B_TOK, 256, 0, stream>>>(x, Wgeff, gbias, gamma, tk_idx, tk_w, counts);
  k_scan<<<1, 64, 0, stream>>>(counts, offsets, cursors);
  k_scatter<<<B_TOK / 256, 256, 0, stream>>>(tk_idx, tk_w, cursors, a_tok, a_w);
  k_encoder<<<dim3(DM / 128, B_TOK / 128), 256, 0, stream>>>(x_bf, We_bf, be, Out, enc_bf);
  k_expert<<<dim3(512, NEXP), 256, 0, stream>>>(enc_bf, U_bf, V_bf, offsets, a_tok, a_w, Out);
}

// Round 2
// 745.880 us; speedup vs baseline: 1.9418x; 1.9418x over previous
//
#include <hip/hip_runtime.h>
#include <stdint.h>

#define B_TOK 32768
#define DM 1024
#define NEXP 16
#define RK 64

typedef unsigned short u16;
typedef __bf16 bf16x8 __attribute__((ext_vector_type(8)));
typedef float f32x4 __attribute__((ext_vector_type(4)));

__device__ __forceinline__ u16 f2bf(float f) {
  union { float f; uint32_t u; } v; v.f = f;
  return (u16)((v.u + 0x7fffu + ((v.u >> 16) & 1u)) >> 16);
}

__device__ __forceinline__ void gload_lds16(const void* g, void* l) {
  __builtin_amdgcn_global_load_lds(
      (const __attribute__((address_space(1))) void*)g,
      (__attribute__((address_space(3))) void*)l, 16, 0, 0);
}

// ---------------- f32 -> bf16 conversion ----------------
__global__ void k_convert(const float* __restrict__ src, u16* __restrict__ dst, int n4) {
  int i = blockIdx.x * blockDim.x + threadIdx.x;
  int stride = gridDim.x * blockDim.x;
  for (; i < n4; i += stride) {
    float4 v = reinterpret_cast<const float4*>(src)[i];
    ushort4 o;
    o.x = f2bf(v.x); o.y = f2bf(v.y); o.z = f2bf(v.z); o.w = f2bf(v.w);
    reinterpret_cast<ushort4*>(dst)[i] = o;
  }
}

// ---------------- fused gating matrix: Wg_eff = Wg @ We, gbias = Wg @ be ----------------
__global__ void k_wgeff(const float* __restrict__ Wg, const float* __restrict__ We,
                        const float* __restrict__ be,
                        float* __restrict__ Wgeff, float* __restrict__ gbias) {
  int e = blockIdx.y;
  int d = blockIdx.x * 256 + threadIdx.x;
  double acc = 0.0;
  for (int k = 0; k < DM; ++k)
    acc += (double)Wg[e * DM + k] * (double)We[k * DM + d];
  Wgeff[e * DM + d] = (float)acc;
  if (blockIdx.x == 0 && threadIdx.x == 0) {
    double s = 0.0;
    for (int k = 0; k < DM; ++k) s += (double)be[k] * (double)Wg[e * DM + k];
    gbias[e] = (float)s;
  }
}

// ---------------- gating v2: tiled LDS GEMM, f64 accum, parallel top-2 ----------------
// 64 tokens per block, K-chunks of 128; micro-tile 2 tokens x 2 experts per thread.
#define GT 64
#define GD 128

__global__ __launch_bounds__(256) void k_gating(
    const float* __restrict__ x, const float* __restrict__ Wgeff,
    const float* __restrict__ gbias, const float* __restrict__ gamma,
    int* __restrict__ tk_idx, float* __restrict__ tk_w, int* __restrict__ counts) {
  __shared__ float xs[GT][GD + 4];    // +4 pad: rows shift 4 banks -> <=2-way alias (free)
  __shared__ float wsd[NEXP][GD + 4];
  __shared__ float lg[GT][NEXP + 2];
  __shared__ int bcnt[NEXP];
  const int tid = threadIdx.x;
  const int tok0 = blockIdx.x * GT;
  const int t0 = (tid >> 3) * 2;   // token pair 0..62
  const int e0 = (tid & 7) * 2;    // expert pair 0..14
  if (tid < NEXP) bcnt[tid] = 0;

  double acc00 = 0.0, acc01 = 0.0, acc10 = 0.0, acc11 = 0.0;

  for (int c = 0; c < DM; c += GD) {
    __syncthreads();
    // stage x tile: 64 rows x 128 f32 = 2048 float4, 8 per thread
    #pragma unroll
    for (int v = 0; v < (GT * GD / 4) / 256; ++v) {
      int idx = tid + v * 256;
      int r = idx >> 5, cc = idx & 31;  // GD/4 = 32 float4/row
      *reinterpret_cast<float4*>(&xs[r][cc * 4]) =
          *reinterpret_cast<const float4*>(x + (size_t)(tok0 + r) * DM + c + cc * 4);
    }
    // stage Wgeff tile: 16 rows x 128 f32 = 512 float4, 2 per thread
    #pragma unroll
    for (int v = 0; v < (NEXP * GD / 4) / 256; ++v) {
      int idx = tid + v * 256;
      int r = idx >> 5, cc = idx & 31;
      *reinterpret_cast<float4*>(&wsd[r][cc * 4]) =
          *reinterpret_cast<const float4*>(Wgeff + (size_t)r * DM + c + cc * 4);
    }
    __syncthreads();
    #pragma unroll 8
    for (int d = 0; d < GD; d += 4) {
      float4 xa = *reinterpret_cast<const float4*>(&xs[t0][d]);
      float4 xb = *reinterpret_cast<const float4*>(&xs[t0 + 1][d]);
      float4 wa = *reinterpret_cast<const float4*>(&wsd[e0][d]);
      float4 wb = *reinterpret_cast<const float4*>(&wsd[e0 + 1][d]);
      acc00 += (double)xa.x * wa.x + (double)xa.y * wa.y + (double)xa.z * wa.z + (double)xa.w * wa.w;
      acc01 += (double)xa.x * wb.x + (double)xa.y * wb.y + (double)xa.z * wb.z + (double)xa.w * wb.w;
      acc10 += (double)xb.x * wa.x + (double)xb.y * wa.y + (double)xb.z * wa.z + (double)xb.w * wa.w;
      acc11 += (double)xb.x * wb.x + (double)xb.y * wb.y + (double)xb.z * wb.z + (double)xb.w * wb.w;
    }
  }

  lg[t0][e0]         = (float)(acc00 + (double)gbias[e0]);
  lg[t0][e0 + 1]     = (float)(acc01 + (double)gbias[e0 + 1]);
  lg[t0 + 1][e0]     = (float)(acc10 + (double)gbias[e0]);
  lg[t0 + 1][e0 + 1] = (float)(acc11 + (double)gbias[e0 + 1]);
  __syncthreads();

  if (tid < GT) {
    int tok = tok0 + tid;
    float v0 = lg[tid][0]; int i0 = 0;
    #pragma unroll
    for (int j = 1; j < NEXP; ++j)
      if (lg[tid][j] > v0) { v0 = lg[tid][j]; i0 = j; }
    float v1 = -3.4e38f; int i1 = 0;
    #pragma unroll
    for (int j = 0; j < NEXP; ++j) {
      if (j == i0) continue;
      if (lg[tid][j] > v1) { v1 = lg[tid][j]; i1 = j; }
    }
    float e1 = expf(v1 - v0);
    float denom = 1.0f + e1 + 1e-12f;
    float w0 = 1.0f / denom, w1 = e1 / denom;
    if (!(w0 > 1e-12f)) w0 = 0.0f;
    if (!(w1 > 1e-12f)) w1 = 0.0f;
    tk_idx[tok * 2 + 0] = i0;
    tk_idx[tok * 2 + 1] = i1;
    tk_w[tok * 2 + 0] = w0 * gamma[i0];
    tk_w[tok * 2 + 1] = w1 * gamma[i1];
    atomicAdd(&bcnt[i0], 1);
    atomicAdd(&bcnt[i1], 1);
  }
  __syncthreads();
  if (tid < NEXP) atomicAdd(&counts[tid], bcnt[tid]);
}

// ---------------- prefix-scan (16 entries) ----------------
__global__ void k_scan(const int* __restrict__ counts, int* __restrict__ offsets,
                       int* __restrict__ cursors) {
  if (threadIdx.x == 0 && blockIdx.x == 0) {
    int s = 0;
    for (int e = 0; e < NEXP; ++e) { offsets[e] = s; cursors[e] = s; s += counts[e]; }
    offsets[NEXP] = s;
  }
}

// ---------------- scatter token assignments into per-expert lists ----------------
__global__ void k_scatter(const int* __restrict__ tk_idx, const float* __restrict__ tk_w,
                          int* __restrict__ cursors, int* __restrict__ a_tok,
                          float* __restrict__ a_w) {
  int tok = blockIdx.x * blockDim.x + threadIdx.x;
  if (tok >= B_TOK) return;
  #pragma unroll
  for (int k = 0; k < 2; ++k) {
    int e = tk_idx[tok * 2 + k];
    int pos = atomicAdd(&cursors[e], 1);
    a_tok[pos] = tok;
    a_w[pos] = tk_w[tok * 2 + k];
  }
}

// ---------------- encoder GEMM: enc = x @ We^T + be (bf16 MFMA, m97 structure) ----------------
__global__ __launch_bounds__(256) void k_encoder(
    const u16* __restrict__ A, const u16* __restrict__ Bm,
    const float* __restrict__ bias, float* __restrict__ Cf, u16* __restrict__ Cb) {
  __shared__ __align__(16) u16 As[128 * 32];
  __shared__ __align__(16) u16 Bs[128 * 32];
  const int m0 = blockIdx.y * 128, n0 = blockIdx.x * 128;
  const int tid = threadIdx.x;
  const int lane = tid & 63, wave = tid >> 6;
  const int wr = wave >> 1, wc = wave & 1;

  f32x4 acc[4][4];
  #pragma unroll
  for (int i = 0; i < 4; ++i)
    #pragma unroll
    for (int j = 0; j < 4; ++j) acc[i][j] = (f32x4){0.f, 0.f, 0.f, 0.f};

  const int srow = tid >> 2;
  const int scol = (tid & 3) * 8;
  const int lrow = lane & 15, lk = (lane >> 4) * 8;

  const u16* ga1 = A + (size_t)(m0 + srow) * DM + scol;
  const u16* ga2 = A + (size_t)(m0 + 64 + srow) * DM + scol;
  const u16* gb1 = Bm + (size_t)(n0 + srow) * DM + scol;
  const u16* gb2 = Bm + (size_t)(n0 + 64 + srow) * DM + scol;

  for (int k0 = 0; k0 < DM; k0 += 32) {
    __syncthreads();
    gload_lds16(ga1 + k0, As + srow * 32 + scol);
    gload_lds16(ga2 + k0, As + (64 + srow) * 32 + scol);
    gload_lds16(gb1 + k0, Bs + srow * 32 + scol);
    gload_lds16(gb2 + k0, Bs + (64 + srow) * 32 + scol);
    __syncthreads();
    bf16x8 a[4], b[4];
    #pragma unroll
    for (int mi = 0; mi < 4; ++mi)
      a[mi] = *reinterpret_cast<const bf16x8*>(&As[(wr * 64 + mi * 16 + lrow) * 32 + lk]);
    #pragma unroll
    for (int nj = 0; nj < 4; ++nj)
      b[nj] = *reinterpret_cast<const bf16x8*>(&Bs[(wc * 64 + nj * 16 + lrow) * 32 + lk]);
    #pragma unroll
    for (int mi = 0; mi < 4; ++mi)
      #pragma unroll
      for (int nj = 0; nj < 4; ++nj)
        acc[mi][nj] = __builtin_amdgcn_mfma_f32_16x16x32_bf16(a[mi], b[nj], acc[mi][nj], 0, 0, 0);
  }

  const int orow = (lane >> 4) * 4, ocol = lane & 15;
  #pragma unroll
  for (int mi = 0; mi < 4; ++mi) {
    #pragma unroll
    for (int nj = 0; nj < 4; ++nj) {
      int gcol = n0 + wc * 64 + nj * 16 + ocol;
      float bv = bias[gcol];
      #pragma unroll
      for (int r = 0; r < 4; ++r) {
        int grow = m0 + wr * 64 + mi * 16 + orow + r;
        float v = acc[mi][nj][r] + bv;
        Cf[(size_t)grow * DM + gcol] = v;
        Cb[(size_t)grow * DM + gcol] = f2bf(v);
      }
    }
  }
}

// ---------------- grouped expert kernel ----------------
__global__ __launch_bounds__(256) void k_expert(
    const u16* __restrict__ Enc, const u16* __restrict__ Ub,
    const u16* __restrict__ Vb, const int* __restrict__ offsets,
    const int* __restrict__ a_tok, const float* __restrict__ a_w,
    float* __restrict__ Out) {
  const int e = blockIdx.y;
  const int base = offsets[e];
  const int cnt = offsets[e + 1] - base;
  const int t0 = blockIdx.x * 64;
  if (t0 >= cnt) return;
  const int tid = threadIdx.x;
  const int lane = tid & 63, wave = tid >> 6;

  __shared__ int s_tok[64];
  __shared__ float s_w[64];
  if (tid < 64) {
    int idx = t0 + tid;
    if (idx < cnt) { s_tok[tid] = a_tok[base + idx]; s_w[tid] = a_w[base + idx]; }
    else           { s_tok[tid] = a_tok[base];       s_w[tid] = 0.0f; }
  }
  __shared__ __align__(16) u16 As[64 * 32];
  __shared__ __align__(16) u16 Bs[64 * 32];
  __shared__ __align__(16) u16 Hs[64 * 72];
  __syncthreads();

  const int srow = tid >> 2, scol = (tid & 3) * 8;
  const int lrow = lane & 15, lk = (lane >> 4) * 8;
  const int wr = wave >> 1, wc = wave & 1;
  const u16* Ue = Ub + (size_t)e * RK * DM;
  const u16* Ve = Vb + (size_t)e * DM * RK;

  const u16* encRow = Enc + (size_t)s_tok[srow] * DM + scol;
  const u16* uRow = Ue + (size_t)srow * DM + scol;

  f32x4 acc1[2][2];
  #pragma unroll
  for (int i = 0; i < 2; ++i)
    #pragma unroll
    for (int j = 0; j < 2; ++j) acc1[i][j] = (f32x4){0.f, 0.f, 0.f, 0.f};

  for (int k0 = 0; k0 < DM; k0 += 32) {
    __syncthreads();
    gload_lds16(encRow + k0, As + srow * 32 + scol);
    gload_lds16(uRow + k0, Bs + srow * 32 + scol);
    __syncthreads();
    bf16x8 a0 = *reinterpret_cast<const bf16x8*>(&As[(wr * 32 + lrow) * 32 + lk]);
    bf16x8 a1 = *reinterpret_cast<const bf16x8*>(&As[(wr * 32 + 16 + lrow) * 32 + lk]);
    bf16x8 b0 = *reinterpret_cast<const bf16x8*>(&Bs[(wc * 32 + lrow) * 32 + lk]);
    bf16x8 b1 = *reinterpret_cast<const bf16x8*>(&Bs[(wc * 32 + 16 + lrow) * 32 + lk]);
    acc1[0][0] = __builtin_amdgcn_mfma_f32_16x16x32_bf16(a0, b0, acc1[0][0], 0, 0, 0);
    acc1[0][1] = __builtin_amdgcn_mfma_f32_16x16x32_bf16(a0, b1, acc1[0][1], 0, 0, 0);
    acc1[1][0] = __builtin_amdgcn_mfma_f32_16x16x32_bf16(a1, b0, acc1[1][0], 0, 0, 0);
    acc1[1][1] = __builtin_amdgcn_mfma_f32_16x16x32_bf16(a1, b1, acc1[1][1], 0, 0, 0);
  }

  #pragma unroll
  for (int mi = 0; mi < 2; ++mi)
    #pragma unroll
    for (int nj = 0; nj < 2; ++nj)
      #pragma unroll
      for (int r = 0; r < 4; ++r) {
        int trow = wr * 32 + mi * 16 + (lane >> 4) * 4 + r;
        int rcol = wc * 32 + nj * 16 + (lane & 15);
        float z = acc1[mi][nj][r];
        float h = z / (1.0f + expf(-z));
        Hs[trow * 72 + rcol] = f2bf(h);
      }
  __syncthreads();

  for (int p = 0; p < 4; ++p) {
    int col0 = p * 256 + wave * 64;
    f32x4 acc2[4][4];
    #pragma unroll
    for (int i = 0; i < 4; ++i)
      #pragma unroll
      for (int j = 0; j < 4; ++j) acc2[i][j] = (f32x4){0.f, 0.f, 0.f, 0.f};
    #pragma unroll
    for (int kk = 0; kk < 2; ++kk) {
      bf16x8 hfrag[4];
      #pragma unroll
      for (int mi = 0; mi < 4; ++mi)
        hfrag[mi] = *reinterpret_cast<const bf16x8*>(&Hs[(mi * 16 + lrow) * 72 + kk * 32 + lk]);
      #pragma unroll
      for (int nj = 0; nj < 4; ++nj) {
        int drow = col0 + nj * 16 + lrow;
        bf16x8 vfrag = *reinterpret_cast<const bf16x8*>(&Ve[(size_t)drow * RK + kk * 32 + lk]);
        #pragma unroll
        for (int mi = 0; mi < 4; ++mi)
          acc2[mi][nj] = __builtin_amdgcn_mfma_f32_16x16x32_bf16(hfrag[mi], vfrag, acc2[mi][nj], 0, 0, 0);
      }
    }
    #pragma unroll
    for (int mi = 0; mi < 4; ++mi)
      #pragma unroll
      for (int nj = 0; nj < 4; ++nj)
        #pragma unroll
        for (int r = 0; r < 4; ++r) {
          int trow = mi * 16 + (lane >> 4) * 4 + r;
          int d = col0 + nj * 16 + (lane & 15);
          float v = acc2[mi][nj][r] * s_w[trow];
          if (v != 0.0f) atomicAdd(&Out[(size_t)s_tok[trow] * DM + d], v);
        }
  }
}

// ---------------- host launch ----------------
extern "C" void kernel_launch(void* const* d_in, const int* in_sizes, int n_in,
                              void* d_out, int out_size, void* d_ws, size_t ws_size,
                              hipStream_t stream) {
  const float* x = (const float*)d_in[0];
  const float* We = (const float*)d_in[1];
  const float* be = (const float*)d_in[2];
  const float* Wg = (const float*)d_in[3];
  const float* U = (const float*)d_in[4];
  const float* V = (const float*)d_in[5];
  const float* gamma = (const float*)d_in[6];
  float* Out = (float*)d_out;

  char* ws = (char*)d_ws;
  size_t off = 0;
  auto alloc = [&](size_t bytes) -> void* {
    void* p = ws + off;
    off += (bytes + 255) & ~(size_t)255;
    return p;
  };
  u16* x_bf   = (u16*)alloc((size_t)B_TOK * DM * 2);
  u16* enc_bf = (u16*)alloc((size_t)B_TOK * DM * 2);
  u16* We_bf  = (u16*)alloc((size_t)DM * DM * 2);
  u16* U_bf   = (u16*)alloc((size_t)NEXP * RK * DM * 2);
  u16* V_bf   = (u16*)alloc((size_t)NEXP * DM * RK * 2);
  float* Wgeff = (float*)alloc((size_t)NEXP * DM * 4);
  float* gbias = (float*)alloc(NEXP * 4);
  int* tk_idx  = (int*)alloc((size_t)B_TOK * 2 * 4);
  float* tk_w  = (float*)alloc((size_t)B_TOK * 2 * 4);
  int* counts  = (int*)alloc(NEXP * 4);
  int* offsets = (int*)alloc((NEXP + 1) * 4);
  int* cursors = (int*)alloc(NEXP * 4);
  int* a_tok   = (int*)alloc((size_t)B_TOK * 2 * 4);
  float* a_w   = (float*)alloc((size_t)B_TOK * 2 * 4);
  (void)ws_size; (void)in_sizes; (void)n_in; (void)out_size;

  hipMemsetAsync(counts, 0, NEXP * 4, stream);

  k_convert<<<2048, 256, 0, stream>>>(x, x_bf, B_TOK * DM / 4);
  k_convert<<<256, 256, 0, stream>>>(We, We_bf, DM * DM / 4);
  k_convert<<<256, 256, 0, stream>>>(U, U_bf, NEXP * RK * DM / 4);
  k_convert<<<256, 256, 0, stream>>>(V, V_bf, NEXP * DM * RK / 4);
  k_wgeff<<<dim3(4, 16), 256, 0, stream>>>(Wg, We, be, Wgeff, gbias);
  k_gating<<<B_TOK / GT, 256, 0, stream>>>(x, Wgeff, gbias, gamma, tk_idx, tk_w, counts);
  k_scan<<<1, 64, 0, stream>>>(counts, offsets, cursors);
  k_scatter<<<B_TOK / 256, 256, 0, stream>>>(tk_idx, tk_w, cursors, a_tok, a_w);
  k_encoder<<<dim3(DM / 128, B_TOK / 128), 256, 0, stream>>>(x_bf, We_bf, be, Out, enc_bf);
  k_expert<<<dim3(512, NEXP), 256, 0, stream>>>(enc_bf, U_bf, V_bf, offsets, a_tok, a_w, Out);
}

// Round 3
// 484.247 us; speedup vs baseline: 2.9909x; 1.5403x over previous
//
#include <hip/hip_runtime.h>
#include <stdint.h>

#define B_TOK 32768
#define DM 1024
#define NEXP 16
#define RK 64
#define NPAIR 256
#define MAXTILE 1024

typedef unsigned short u16;
typedef __bf16 bf16x8 __attribute__((ext_vector_type(8)));
typedef float f32x4 __attribute__((ext_vector_type(4)));

__device__ __forceinline__ u16 f2bf(float f) {
  union { float f; uint32_t u; } v; v.f = f;
  return (u16)((v.u + 0x7fffu + ((v.u >> 16) & 1u)) >> 16);
}
__device__ __forceinline__ float bf2f(u16 u) {
  union { uint32_t i; float f; } v; v.i = ((uint32_t)u) << 16; return v.f;
}

__device__ __forceinline__ void gload_lds16(const void* g, void* l) {
  __builtin_amdgcn_global_load_lds(
      (const __attribute__((address_space(1))) void*)g,
      (__attribute__((address_space(3))) void*)l, 16, 0, 0);
}

// ---------------- f32 -> bf16 conversion ----------------
__global__ void k_convert(const float* __restrict__ src, u16* __restrict__ dst, int n4) {
  int i = blockIdx.x * blockDim.x + threadIdx.x;
  int stride = gridDim.x * blockDim.x;
  for (; i < n4; i += stride) {
    float4 v = reinterpret_cast<const float4*>(src)[i];
    ushort4 o;
    o.x = f2bf(v.x); o.y = f2bf(v.y); o.z = f2bf(v.z); o.w = f2bf(v.w);
    reinterpret_cast<ushort4*>(dst)[i] = o;
  }
}

// ---------------- fused gating matrix: Wg_eff = Wg @ We, gbias = Wg @ be ----------------
__global__ void k_wgeff(const float* __restrict__ Wg, const float* __restrict__ We,
                        const float* __restrict__ be,
                        float* __restrict__ Wgeff, float* __restrict__ gbias) {
  int e = blockIdx.y;
  int d = blockIdx.x * 256 + threadIdx.x;
  double acc = 0.0;
  for (int k = 0; k < DM; ++k)
    acc += (double)Wg[e * DM + k] * (double)We[k * DM + d];
  Wgeff[e * DM + d] = (float)acc;
  if (blockIdx.x == 0 && threadIdx.x == 0) {
    double s = 0.0;
    for (int k = 0; k < DM; ++k) s += (double)be[k] * (double)Wg[e * DM + k];
    gbias[e] = (float)s;
  }
}

// ---------------- gating: tiled LDS GEMM, f64 accum, parallel top-2, pair-id out ----------------
#define GT 64
#define GD 128

__global__ __launch_bounds__(256) void k_gating(
    const float* __restrict__ x, const float* __restrict__ Wgeff,
    const float* __restrict__ gbias, const float* __restrict__ gamma,
    int* __restrict__ tk_pid, float* __restrict__ tk_w0, float* __restrict__ tk_w1,
    int* __restrict__ counts) {
  __shared__ float xs[GT][GD + 4];
  __shared__ float wsd[NEXP][GD + 4];
  __shared__ float lg[GT][NEXP + 2];
  __shared__ int bcnt[NPAIR];
  const int tid = threadIdx.x;
  const int tok0 = blockIdx.x * GT;
  const int t0 = (tid >> 3) * 2;
  const int e0 = (tid & 7) * 2;
  bcnt[tid] = 0;

  double acc00 = 0.0, acc01 = 0.0, acc10 = 0.0, acc11 = 0.0;

  for (int c = 0; c < DM; c += GD) {
    __syncthreads();
    #pragma unroll
    for (int v = 0; v < (GT * GD / 4) / 256; ++v) {
      int idx = tid + v * 256;
      int r = idx >> 5, cc = idx & 31;
      *reinterpret_cast<float4*>(&xs[r][cc * 4]) =
          *reinterpret_cast<const float4*>(x + (size_t)(tok0 + r) * DM + c + cc * 4);
    }
    #pragma unroll
    for (int v = 0; v < (NEXP * GD / 4) / 256; ++v) {
      int idx = tid + v * 256;
      int r = idx >> 5, cc = idx & 31;
      *reinterpret_cast<float4*>(&wsd[r][cc * 4]) =
          *reinterpret_cast<const float4*>(Wgeff + (size_t)r * DM + c + cc * 4);
    }
    __syncthreads();
    #pragma unroll 8
    for (int d = 0; d < GD; d += 4) {
      float4 xa = *reinterpret_cast<const float4*>(&xs[t0][d]);
      float4 xb = *reinterpret_cast<const float4*>(&xs[t0 + 1][d]);
      float4 wa = *reinterpret_cast<const float4*>(&wsd[e0][d]);
      float4 wb = *reinterpret_cast<const float4*>(&wsd[e0 + 1][d]);
      acc00 += (double)xa.x * wa.x + (double)xa.y * wa.y + (double)xa.z * wa.z + (double)xa.w * wa.w;
      acc01 += (double)xa.x * wb.x + (double)xa.y * wb.y + (double)xa.z * wb.z + (double)xa.w * wb.w;
      acc10 += (double)xb.x * wa.x + (double)xb.y * wa.y + (double)xb.z * wa.z + (double)xb.w * wa.w;
      acc11 += (double)xb.x * wb.x + (double)xb.y * wb.y + (double)xb.z * wb.z + (double)xb.w * wb.w;
    }
  }

  lg[t0][e0]         = (float)(acc00 + (double)gbias[e0]);
  lg[t0][e0 + 1]     = (float)(acc01 + (double)gbias[e0 + 1]);
  lg[t0 + 1][e0]     = (float)(acc10 + (double)gbias[e0]);
  lg[t0 + 1][e0 + 1] = (float)(acc11 + (double)gbias[e0 + 1]);
  __syncthreads();

  if (tid < GT) {
    int tok = tok0 + tid;
    float v0 = lg[tid][0]; int i0 = 0;
    #pragma unroll
    for (int j = 1; j < NEXP; ++j)
      if (lg[tid][j] > v0) { v0 = lg[tid][j]; i0 = j; }
    float v1 = -3.4e38f; int i1 = 0;
    #pragma unroll
    for (int j = 0; j < NEXP; ++j) {
      if (j == i0) continue;
      if (lg[tid][j] > v1) { v1 = lg[tid][j]; i1 = j; }
    }
    float e1 = expf(v1 - v0);
    float denom = 1.0f + e1 + 1e-12f;
    float w0 = 1.0f / denom, w1 = e1 / denom;
    if (!(w0 > 1e-12f)) w0 = 0.0f;
    if (!(w1 > 1e-12f)) w1 = 0.0f;
    int pid = i0 * 16 + i1;
    tk_pid[tok] = pid;
    tk_w0[tok] = w0 * gamma[i0];
    tk_w1[tok] = w1 * gamma[i1];
    atomicAdd(&bcnt[pid], 1);
  }
  __syncthreads();
  if (bcnt[tid] > 0) atomicAdd(&counts[tid], bcnt[tid]);
}

// ---------------- scan over 256 pairs + tile table build ----------------
__global__ void k_scan(const int* __restrict__ counts, int* __restrict__ offsets,
                       int* __restrict__ cursors, int* __restrict__ tile_pair,
                       int* __restrict__ tile_loc, int* __restrict__ n_tiles) {
  if (threadIdx.x == 0 && blockIdx.x == 0) {
    int s = 0, nt = 0;
    for (int p = 0; p < NPAIR; ++p) {
      offsets[p] = s; cursors[p] = s;
      int c = counts[p];
      for (int q = 0; q < c; q += 64) { tile_pair[nt] = p; tile_loc[nt] = q; ++nt; }
      s += c;
    }
    offsets[NPAIR] = s;
    n_tiles[0] = nt;
  }
}

// ---------------- scatter tokens into per-pair lists ----------------
__global__ void k_scatter(const int* __restrict__ tk_pid, const float* __restrict__ tk_w0,
                          const float* __restrict__ tk_w1, int* __restrict__ cursors,
                          int* __restrict__ a_tok, float* __restrict__ a_w0,
                          float* __restrict__ a_w1) {
  int tok = blockIdx.x * blockDim.x + threadIdx.x;
  if (tok >= B_TOK) return;
  int pid = tk_pid[tok];
  int pos = atomicAdd(&cursors[pid], 1);
  a_tok[pos] = tok;
  a_w0[pos] = tk_w0[tok];
  a_w1[pos] = tk_w1[tok];
}

// ---------------- encoder GEMM: enc_bf = bf16(x @ We^T + be) ----------------
__global__ __launch_bounds__(256) void k_encoder(
    const u16* __restrict__ A, const u16* __restrict__ Bm,
    const float* __restrict__ bias, u16* __restrict__ Cb) {
  __shared__ __align__(16) u16 As[128 * 32];
  __shared__ __align__(16) u16 Bs[128 * 32];
  const int m0 = blockIdx.y * 128, n0 = blockIdx.x * 128;
  const int tid = threadIdx.x;
  const int lane = tid & 63, wave = tid >> 6;
  const int wr = wave >> 1, wc = wave & 1;

  f32x4 acc[4][4];
  #pragma unroll
  for (int i = 0; i < 4; ++i)
    #pragma unroll
    for (int j = 0; j < 4; ++j) acc[i][j] = (f32x4){0.f, 0.f, 0.f, 0.f};

  const int srow = tid >> 2;
  const int scol = (tid & 3) * 8;
  const int lrow = lane & 15, lk = (lane >> 4) * 8;

  const u16* ga1 = A + (size_t)(m0 + srow) * DM + scol;
  const u16* ga2 = A + (size_t)(m0 + 64 + srow) * DM + scol;
  const u16* gb1 = Bm + (size_t)(n0 + srow) * DM + scol;
  const u16* gb2 = Bm + (size_t)(n0 + 64 + srow) * DM + scol;

  for (int k0 = 0; k0 < DM; k0 += 32) {
    __syncthreads();
    gload_lds16(ga1 + k0, As + srow * 32 + scol);
    gload_lds16(ga2 + k0, As + (64 + srow) * 32 + scol);
    gload_lds16(gb1 + k0, Bs + srow * 32 + scol);
    gload_lds16(gb2 + k0, Bs + (64 + srow) * 32 + scol);
    __syncthreads();
    bf16x8 a[4], b[4];
    #pragma unroll
    for (int mi = 0; mi < 4; ++mi)
      a[mi] = *reinterpret_cast<const bf16x8*>(&As[(wr * 64 + mi * 16 + lrow) * 32 + lk]);
    #pragma unroll
    for (int nj = 0; nj < 4; ++nj)
      b[nj] = *reinterpret_cast<const bf16x8*>(&Bs[(wc * 64 + nj * 16 + lrow) * 32 + lk]);
    #pragma unroll
    for (int mi = 0; mi < 4; ++mi)
      #pragma unroll
      for (int nj = 0; nj < 4; ++nj)
        acc[mi][nj] = __builtin_amdgcn_mfma_f32_16x16x32_bf16(a[mi], b[nj], acc[mi][nj], 0, 0, 0);
  }

  const int orow = (lane >> 4) * 4, ocol = lane & 15;
  #pragma unroll
  for (int mi = 0; mi < 4; ++mi) {
    #pragma unroll
    for (int nj = 0; nj < 4; ++nj) {
      int gcol = n0 + wc * 64 + nj * 16 + ocol;
      float bv = bias[gcol];
      #pragma unroll
      for (int r = 0; r < 4; ++r) {
        int grow = m0 + wr * 64 + mi * 16 + orow + r;
        Cb[(size_t)grow * DM + gcol] = f2bf(acc[mi][nj][r] + bv);
      }
    }
  }
}

// ---------------- pair-grouped expert kernel: no atomics, writes final Out ----------------
// stage1: C1[64 tok x 128] = enc @ [U_e0; U_e1]^T ; H = silu(C1)*w (bf16, LDS)
// stage2: acc[d][tok] = Vcat-as-A x H-as-B MFMA -> Out[tok][d] = enc + acc (float4 stores)
#define HS_STRIDE 136

__global__ __launch_bounds__(256) void k_expert(
    const u16* __restrict__ Enc, const u16* __restrict__ Ub,
    const u16* __restrict__ Vb, const int* __restrict__ offsets,
    const int* __restrict__ tile_pair, const int* __restrict__ tile_loc,
    const int* __restrict__ n_tiles, const int* __restrict__ a_tok,
    const float* __restrict__ a_w0, const float* __restrict__ a_w1,
    float* __restrict__ Out) {
  const int t = blockIdx.x;
  if (t >= n_tiles[0]) return;
  const int pid = tile_pair[t];
  const int pe0 = pid >> 4, pe1 = pid & 15;
  const int base = offsets[pid];
  const int cnt = offsets[pid + 1] - base;
  const int loc0 = tile_loc[t];
  const int tid = threadIdx.x;
  const int lane = tid & 63, wave = tid >> 6;

  __shared__ int s_tok[64];
  __shared__ int s_val[64];
  __shared__ float s_w[2][64];
  if (tid < 64) {
    int idx = loc0 + tid;
    int v = idx < cnt;
    int p = base + (v ? idx : 0);
    s_val[tid] = v;
    s_tok[tid] = a_tok[p];
    s_w[0][tid] = v ? a_w0[p] : 0.0f;
    s_w[1][tid] = v ? a_w1[p] : 0.0f;
  }
  __shared__ __align__(16) u16 As[64 * 32];
  __shared__ __align__(16) u16 Bs[128 * 32];
  __shared__ __align__(16) u16 Hs[64 * HS_STRIDE];
  __syncthreads();

  const int srow = tid >> 2, scol = (tid & 3) * 8;
  const int lrow = lane & 15, lk = (lane >> 4) * 8;

  const u16* encRow = Enc + (size_t)s_tok[srow] * DM + scol;
  const u16* u0Row = Ub + ((size_t)pe0 * RK + srow) * DM + scol;
  const u16* u1Row = Ub + ((size_t)pe1 * RK + srow) * DM + scol;

  // ---- stage 1: [64 tok x 128 rcol], K = 1024 ----
  f32x4 acc1[4][2];
  #pragma unroll
  for (int i = 0; i < 4; ++i) {
    acc1[i][0] = (f32x4){0.f, 0.f, 0.f, 0.f};
    acc1[i][1] = (f32x4){0.f, 0.f, 0.f, 0.f};
  }

  for (int k0 = 0; k0 < DM; k0 += 32) {
    __syncthreads();
    gload_lds16(encRow + k0, As + srow * 32 + scol);
    gload_lds16(u0Row + k0, Bs + srow * 32 + scol);
    gload_lds16(u1Row + k0, Bs + (64 + srow) * 32 + scol);
    __syncthreads();
    bf16x8 b0 = *reinterpret_cast<const bf16x8*>(&Bs[(wave * 32 + lrow) * 32 + lk]);
    bf16x8 b1 = *reinterpret_cast<const bf16x8*>(&Bs[(wave * 32 + 16 + lrow) * 32 + lk]);
    #pragma unroll
    for (int mi = 0; mi < 4; ++mi) {
      bf16x8 a = *reinterpret_cast<const bf16x8*>(&As[(mi * 16 + lrow) * 32 + lk]);
      acc1[mi][0] = __builtin_amdgcn_mfma_f32_16x16x32_bf16(a, b0, acc1[mi][0], 0, 0, 0);
      acc1[mi][1] = __builtin_amdgcn_mfma_f32_16x16x32_bf16(a, b1, acc1[mi][1], 0, 0, 0);
    }
  }

  // silu * routing weight -> Hs (wave w owns rcols [w*32, w*32+32); side = w>>1)
  {
    const int side = wave >> 1;
    #pragma unroll
    for (int mi = 0; mi < 4; ++mi)
      #pragma unroll
      for (int cj = 0; cj < 2; ++cj)
        #pragma unroll
        for (int r = 0; r < 4; ++r) {
          int tok = mi * 16 + (lane >> 4) * 4 + r;
          int col = wave * 32 + cj * 16 + (lane & 15);
          float z = acc1[mi][cj][r];
          float h = z / (1.0f + expf(-z)) * s_w[side][tok];
          Hs[tok * HS_STRIDE + col] = f2bf(h);
        }
  }
  __syncthreads();

  // ---- stage 2: D[d][tok] = Vcat(A) x H(B), K=128; write Out = enc + D ----
  const u16* V0 = Vb + (size_t)pe0 * DM * RK;
  const u16* V1 = Vb + (size_t)pe1 * DM * RK;

  for (int p = 0; p < 4; ++p) {
    const int d0w = p * 256 + wave * 64;
    f32x4 acc2[4][4];
    #pragma unroll
    for (int i = 0; i < 4; ++i)
      #pragma unroll
      for (int j = 0; j < 4; ++j) acc2[i][j] = (f32x4){0.f, 0.f, 0.f, 0.f};

    #pragma unroll
    for (int kk = 0; kk < 4; ++kk) {
      bf16x8 hb[4];
      #pragma unroll
      for (int tf = 0; tf < 4; ++tf)
        hb[tf] = *reinterpret_cast<const bf16x8*>(&Hs[(tf * 16 + lrow) * HS_STRIDE + kk * 32 + lk]);
      #pragma unroll
      for (int mi = 0; mi < 4; ++mi) {
        int d = d0w + mi * 16 + lrow;
        const u16* vp = (kk < 2) ? (V0 + (size_t)d * RK + kk * 32 + lk)
                                 : (V1 + (size_t)d * RK + (kk - 2) * 32 + lk);
        bf16x8 va = *reinterpret_cast<const bf16x8*>(vp);
        #pragma unroll
        for (int tf = 0; tf < 4; ++tf)
          acc2[mi][tf] = __builtin_amdgcn_mfma_f32_16x16x32_bf16(va, hb[tf], acc2[mi][tf], 0, 0, 0);
      }
    }

    // epilogue: lane holds 4 consecutive d for token (lane&15); float4 store
    #pragma unroll
    for (int mi = 0; mi < 4; ++mi)
      #pragma unroll
      for (int tf = 0; tf < 4; ++tf) {
        int tok = tf * 16 + (lane & 15);
        if (!s_val[tok]) continue;
        int d = d0w + mi * 16 + (lane >> 4) * 4;
        size_t rowoff = (size_t)s_tok[tok] * DM + d;
        ushort4 ev = *reinterpret_cast<const ushort4*>(Enc + rowoff);
        float4 o;
        o.x = acc2[mi][tf][0] + bf2f(ev.x);
        o.y = acc2[mi][tf][1] + bf2f(ev.y);
        o.z = acc2[mi][tf][2] + bf2f(ev.z);
        o.w = acc2[mi][tf][3] + bf2f(ev.w);
        *reinterpret_cast<float4*>(Out + rowoff) = o;
      }
  }
}

// ---------------- host launch ----------------
extern "C" void kernel_launch(void* const* d_in, const int* in_sizes, int n_in,
                              void* d_out, int out_size, void* d_ws, size_t ws_size,
                              hipStream_t stream) {
  const float* x = (const float*)d_in[0];
  const float* We = (const float*)d_in[1];
  const float* be = (const float*)d_in[2];
  const float* Wg = (const float*)d_in[3];
  const float* U = (const float*)d_in[4];
  const float* V = (const float*)d_in[5];
  const float* gamma = (const float*)d_in[6];
  float* Out = (float*)d_out;

  char* ws = (char*)d_ws;
  size_t off = 0;
  auto alloc = [&](size_t bytes) -> void* {
    void* p = ws + off;
    off += (bytes + 255) & ~(size_t)255;
    return p;
  };
  u16* x_bf   = (u16*)alloc((size_t)B_TOK * DM * 2);
  u16* enc_bf = (u16*)alloc((size_t)B_TOK * DM * 2);
  u16* We_bf  = (u16*)alloc((size_t)DM * DM * 2);
  u16* U_bf   = (u16*)alloc((size_t)NEXP * RK * DM * 2);
  u16* V_bf   = (u16*)alloc((size_t)NEXP * DM * RK * 2);
  float* Wgeff = (float*)alloc((size_t)NEXP * DM * 4);
  float* gbias = (float*)alloc(NEXP * 4);
  int* tk_pid  = (int*)alloc((size_t)B_TOK * 4);
  float* tk_w0 = (float*)alloc((size_t)B_TOK * 4);
  float* tk_w1 = (float*)alloc((size_t)B_TOK * 4);
  int* counts  = (int*)alloc(NPAIR * 4);
  int* offsets = (int*)alloc((NPAIR + 1) * 4);
  int* cursors = (int*)alloc(NPAIR * 4);
  int* tile_pair = (int*)alloc(MAXTILE * 4);
  int* tile_loc  = (int*)alloc(MAXTILE * 4);
  int* n_tiles   = (int*)alloc(256);
  int* a_tok   = (int*)alloc((size_t)B_TOK * 4);
  float* a_w0  = (float*)alloc((size_t)B_TOK * 4);
  float* a_w1  = (float*)alloc((size_t)B_TOK * 4);
  (void)ws_size; (void)in_sizes; (void)n_in; (void)out_size;

  hipMemsetAsync(counts, 0, NPAIR * 4, stream);

  k_convert<<<2048, 256, 0, stream>>>(x, x_bf, B_TOK * DM / 4);
  k_convert<<<256, 256, 0, stream>>>(We, We_bf, DM * DM / 4);
  k_convert<<<256, 256, 0, stream>>>(U, U_bf, NEXP * RK * DM / 4);
  k_convert<<<256, 256, 0, stream>>>(V, V_bf, NEXP * DM * RK / 4);
  k_wgeff<<<dim3(4, 16), 256, 0, stream>>>(Wg, We, be, Wgeff, gbias);
  k_gating<<<B_TOK / GT, 256, 0, stream>>>(x, Wgeff, gbias, gamma,
                                           tk_pid, tk_w0, tk_w1, counts);
  k_scan<<<1, 64, 0, stream>>>(counts, offsets, cursors, tile_pair, tile_loc, n_tiles);
  k_scatter<<<B_TOK / 256, 256, 0, stream>>>(tk_pid, tk_w0, tk_w1, cursors,
                                             a_tok, a_w0, a_w1);
  k_encoder<<<dim3(DM / 128, B_TOK / 128), 256, 0, stream>>>(x_bf, We_bf, be, enc_bf);
  k_expert<<<MAXTILE, 256, 0, stream>>>(enc_bf, U_bf, V_bf, offsets, tile_pair, tile_loc,
                                        n_tiles, a_tok, a_w0, a_w1, Out);
}

// Round 4
// 426.863 us; speedup vs baseline: 3.3930x; 1.1344x over previous
//
#include <hip/hip_runtime.h>
#include <stdint.h>

#define B_TOK 32768
#define DM 1024
#define NEXP 16
#define RK 64
#define NPAIR 256
#define TPT 16            // tokens per expert tile
#define MAXTILE 2560      // >= 2048 + 256 worst case
#define GRID_EXP 2304

typedef unsigned short u16;
typedef __bf16 bf16x8 __attribute__((ext_vector_type(8)));
typedef float f32x4 __attribute__((ext_vector_type(4)));

__device__ __forceinline__ u16 f2bf(float f) {
  union { float f; uint32_t u; } v; v.f = f;
  return (u16)((v.u + 0x7fffu + ((v.u >> 16) & 1u)) >> 16);
}
__device__ __forceinline__ float bf2f(u16 u) {
  union { uint32_t i; float f; } v; v.i = ((uint32_t)u) << 16; return v.f;
}

__device__ __forceinline__ void gload_lds16(const void* g, void* l) {
  __builtin_amdgcn_global_load_lds(
      (const __attribute__((address_space(1))) void*)g,
      (__attribute__((address_space(3))) void*)l, 16, 0, 0);
}

// ---------------- f32 -> bf16 conversion (weights only now) ----------------
__global__ void k_convert(const float* __restrict__ src, u16* __restrict__ dst, int n4) {
  int i = blockIdx.x * blockDim.x + threadIdx.x;
  int stride = gridDim.x * blockDim.x;
  for (; i < n4; i += stride) {
    float4 v = reinterpret_cast<const float4*>(src)[i];
    ushort4 o;
    o.x = f2bf(v.x); o.y = f2bf(v.y); o.z = f2bf(v.z); o.w = f2bf(v.w);
    reinterpret_cast<ushort4*>(dst)[i] = o;
  }
}

// ---------------- fused gating matrix: Wg_eff = Wg @ We, gbias = Wg @ be ----------------
__global__ void k_wgeff(const float* __restrict__ Wg, const float* __restrict__ We,
                        const float* __restrict__ be,
                        float* __restrict__ Wgeff, float* __restrict__ gbias) {
  int e = blockIdx.y;
  int d = blockIdx.x * 256 + threadIdx.x;
  double acc = 0.0;
  for (int k = 0; k < DM; ++k)
    acc += (double)Wg[e * DM + k] * (double)We[k * DM + d];
  Wgeff[e * DM + d] = (float)acc;
  if (blockIdx.x == 0 && threadIdx.x == 0) {
    double s = 0.0;
    for (int k = 0; k < DM; ++k) s += (double)be[k] * (double)Wg[e * DM + k];
    gbias[e] = (float)s;
  }
}

// ---------------- gating: tiled LDS GEMM (f64 acc) + fused x->bf16 + top-2 ----------------
#define GT 64
#define GD 128

__global__ __launch_bounds__(256) void k_gating(
    const float* __restrict__ x, u16* __restrict__ x_bf,
    const float* __restrict__ Wgeff, const float* __restrict__ gbias,
    const float* __restrict__ gamma,
    int* __restrict__ tk_pid, float* __restrict__ tk_w0, float* __restrict__ tk_w1,
    int* __restrict__ counts) {
  __shared__ float xs[GT][GD + 4];
  __shared__ float wsd[NEXP][GD + 4];
  __shared__ float lg[GT][NEXP + 2];
  __shared__ int bcnt[NPAIR];
  const int tid = threadIdx.x;
  const int tok0 = blockIdx.x * GT;
  const int t0 = (tid >> 3) * 2;
  const int e0 = (tid & 7) * 2;
  bcnt[tid] = 0;

  double acc00 = 0.0, acc01 = 0.0, acc10 = 0.0, acc11 = 0.0;

  for (int c = 0; c < DM; c += GD) {
    __syncthreads();
    #pragma unroll
    for (int v = 0; v < (GT * GD / 4) / 256; ++v) {
      int idx = tid + v * 256;
      int r = idx >> 5, cc = idx & 31;
      float4 v4 = *reinterpret_cast<const float4*>(x + (size_t)(tok0 + r) * DM + c + cc * 4);
      *reinterpret_cast<float4*>(&xs[r][cc * 4]) = v4;
      ushort4 o;
      o.x = f2bf(v4.x); o.y = f2bf(v4.y); o.z = f2bf(v4.z); o.w = f2bf(v4.w);
      *reinterpret_cast<ushort4*>(x_bf + (size_t)(tok0 + r) * DM + c + cc * 4) = o;
    }
    #pragma unroll
    for (int v = 0; v < (NEXP * GD / 4) / 256; ++v) {
      int idx = tid + v * 256;
      int r = idx >> 5, cc = idx & 31;
      *reinterpret_cast<float4*>(&wsd[r][cc * 4]) =
          *reinterpret_cast<const float4*>(Wgeff + (size_t)r * DM + c + cc * 4);
    }
    __syncthreads();
    #pragma unroll 8
    for (int d = 0; d < GD; d += 4) {
      float4 xa = *reinterpret_cast<const float4*>(&xs[t0][d]);
      float4 xb = *reinterpret_cast<const float4*>(&xs[t0 + 1][d]);
      float4 wa = *reinterpret_cast<const float4*>(&wsd[e0][d]);
      float4 wb = *reinterpret_cast<const float4*>(&wsd[e0 + 1][d]);
      acc00 += (double)xa.x * wa.x + (double)xa.y * wa.y + (double)xa.z * wa.z + (double)xa.w * wa.w;
      acc01 += (double)xa.x * wb.x + (double)xa.y * wb.y + (double)xa.z * wb.z + (double)xa.w * wb.w;
      acc10 += (double)xb.x * wa.x + (double)xb.y * wa.y + (double)xb.z * wa.z + (double)xb.w * wa.w;
      acc11 += (double)xb.x * wb.x + (double)xb.y * wb.y + (double)xb.z * wb.z + (double)xb.w * wb.w;
    }
  }

  lg[t0][e0]         = (float)(acc00 + (double)gbias[e0]);
  lg[t0][e0 + 1]     = (float)(acc01 + (double)gbias[e0 + 1]);
  lg[t0 + 1][e0]     = (float)(acc10 + (double)gbias[e0]);
  lg[t0 + 1][e0 + 1] = (float)(acc11 + (double)gbias[e0 + 1]);
  __syncthreads();

  if (tid < GT) {
    int tok = tok0 + tid;
    float v0 = lg[tid][0]; int i0 = 0;
    #pragma unroll
    for (int j = 1; j < NEXP; ++j)
      if (lg[tid][j] > v0) { v0 = lg[tid][j]; i0 = j; }
    float v1 = -3.4e38f; int i1 = 0;
    #pragma unroll
    for (int j = 0; j < NEXP; ++j) {
      if (j == i0) continue;
      if (lg[tid][j] > v1) { v1 = lg[tid][j]; i1 = j; }
    }
    float e1 = expf(v1 - v0);
    float denom = 1.0f + e1 + 1e-12f;
    float w0 = 1.0f / denom, w1 = e1 / denom;
    if (!(w0 > 1e-12f)) w0 = 0.0f;
    if (!(w1 > 1e-12f)) w1 = 0.0f;
    int pid = i0 * 16 + i1;
    tk_pid[tok] = pid;
    tk_w0[tok] = w0 * gamma[i0];
    tk_w1[tok] = w1 * gamma[i1];
    atomicAdd(&bcnt[pid], 1);
  }
  __syncthreads();
  if (bcnt[tid] > 0) atomicAdd(&counts[tid], bcnt[tid]);
}

// ---------------- parallel scan over 256 pairs + tile table build ----------------
__global__ __launch_bounds__(NPAIR) void k_scan(
    const int* __restrict__ counts, int* __restrict__ offsets,
    int* __restrict__ cursors, int* __restrict__ tile_pair,
    int* __restrict__ tile_loc, int* __restrict__ n_tiles) {
  __shared__ int sc[NPAIR], st[NPAIR];
  const int tid = threadIdx.x;
  const int c = counts[tid];
  const int ntile = (c + TPT - 1) / TPT;
  sc[tid] = c; st[tid] = ntile;
  __syncthreads();
  for (int s = 1; s < NPAIR; s <<= 1) {
    int vc = 0, vt = 0;
    if (tid >= s) { vc = sc[tid - s]; vt = st[tid - s]; }
    __syncthreads();
    sc[tid] += vc; st[tid] += vt;
    __syncthreads();
  }
  const int offc = sc[tid] - c;
  const int offt = st[tid] - ntile;
  offsets[tid] = offc;
  cursors[tid] = offc;
  if (tid == NPAIR - 1) { offsets[NPAIR] = sc[tid]; n_tiles[0] = st[tid]; }
  for (int q = 0; q < ntile; ++q) {
    tile_pair[offt + q] = tid;
    tile_loc[offt + q] = q * TPT;
  }
}

// ---------------- scatter tokens into per-pair lists ----------------
__global__ void k_scatter(const int* __restrict__ tk_pid, const float* __restrict__ tk_w0,
                          const float* __restrict__ tk_w1, int* __restrict__ cursors,
                          int* __restrict__ a_tok, float* __restrict__ a_w0,
                          float* __restrict__ a_w1) {
  int tok = blockIdx.x * blockDim.x + threadIdx.x;
  if (tok >= B_TOK) return;
  int pid = tk_pid[tok];
  int pos = atomicAdd(&cursors[pid], 1);
  a_tok[pos] = tok;
  a_w0[pos] = tk_w0[tok];
  a_w1[pos] = tk_w1[tok];
}

// ---------------- encoder GEMM: enc_bf = bf16(x @ We^T + be) ----------------
__global__ __launch_bounds__(256) void k_encoder(
    const u16* __restrict__ A, const u16* __restrict__ Bm,
    const float* __restrict__ bias, u16* __restrict__ Cb) {
  __shared__ __align__(16) u16 As[128 * 32];
  __shared__ __align__(16) u16 Bs[128 * 32];
  const int m0 = blockIdx.y * 128, n0 = blockIdx.x * 128;
  const int tid = threadIdx.x;
  const int lane = tid & 63, wave = tid >> 6;
  const int wr = wave >> 1, wc = wave & 1;

  f32x4 acc[4][4];
  #pragma unroll
  for (int i = 0; i < 4; ++i)
    #pragma unroll
    for (int j = 0; j < 4; ++j) acc[i][j] = (f32x4){0.f, 0.f, 0.f, 0.f};

  const int srow = tid >> 2;
  const int scol = (tid & 3) * 8;
  const int lrow = lane & 15, lk = (lane >> 4) * 8;

  const u16* ga1 = A + (size_t)(m0 + srow) * DM + scol;
  const u16* ga2 = A + (size_t)(m0 + 64 + srow) * DM + scol;
  const u16* gb1 = Bm + (size_t)(n0 + srow) * DM + scol;
  const u16* gb2 = Bm + (size_t)(n0 + 64 + srow) * DM + scol;

  for (int k0 = 0; k0 < DM; k0 += 32) {
    __syncthreads();
    gload_lds16(ga1 + k0, As + srow * 32 + scol);
    gload_lds16(ga2 + k0, As + (64 + srow) * 32 + scol);
    gload_lds16(gb1 + k0, Bs + srow * 32 + scol);
    gload_lds16(gb2 + k0, Bs + (64 + srow) * 32 + scol);
    __syncthreads();
    bf16x8 a[4], b[4];
    #pragma unroll
    for (int mi = 0; mi < 4; ++mi)
      a[mi] = *reinterpret_cast<const bf16x8*>(&As[(wr * 64 + mi * 16 + lrow) * 32 + lk]);
    #pragma unroll
    for (int nj = 0; nj < 4; ++nj)
      b[nj] = *reinterpret_cast<const bf16x8*>(&Bs[(wc * 64 + nj * 16 + lrow) * 32 + lk]);
    #pragma unroll
    for (int mi = 0; mi < 4; ++mi)
      #pragma unroll
      for (int nj = 0; nj < 4; ++nj)
        acc[mi][nj] = __builtin_amdgcn_mfma_f32_16x16x32_bf16(a[mi], b[nj], acc[mi][nj], 0, 0, 0);
  }

  const int orow = (lane >> 4) * 4, ocol = lane & 15;
  #pragma unroll
  for (int mi = 0; mi < 4; ++mi) {
    #pragma unroll
    for (int nj = 0; nj < 4; ++nj) {
      int gcol = n0 + wc * 64 + nj * 16 + ocol;
      float bv = bias[gcol];
      #pragma unroll
      for (int r = 0; r < 4; ++r) {
        int grow = m0 + wr * 64 + mi * 16 + orow + r;
        Cb[(size_t)grow * DM + gcol] = f2bf(acc[mi][nj][r] + bv);
      }
    }
  }
}

// ---------------- pair-grouped expert kernel, 16-token tiles, no atomics ----------------
// stage1: C1[16 tok x 128] = enc @ [U_e0;U_e1]^T ; H = silu(C1)*w (bf16, LDS)
// stage2: per wave: 256 d-cols; acc[d][tok] = V(A) x H(B); Out = enc + acc (float4)
#define HS_STRIDE 136

__global__ __launch_bounds__(256) void k_expert(
    const u16* __restrict__ Enc, const u16* __restrict__ Ub,
    const u16* __restrict__ Vb, const int* __restrict__ offsets,
    const int* __restrict__ tile_pair, const int* __restrict__ tile_loc,
    const int* __restrict__ n_tiles, const int* __restrict__ a_tok,
    const float* __restrict__ a_w0, const float* __restrict__ a_w1,
    float* __restrict__ Out) {
  const int t = blockIdx.x;
  if (t >= n_tiles[0]) return;
  const int pid = tile_pair[t];
  const int pe0 = pid >> 4, pe1 = pid & 15;
  const int base = offsets[pid];
  const int cnt = offsets[pid + 1] - base;
  const int loc0 = tile_loc[t];
  const int tid = threadIdx.x;
  const int lane = tid & 63, wave = tid >> 6;

  __shared__ int s_tok[TPT];
  __shared__ int s_val[TPT];
  __shared__ float s_w[2][TPT];
  if (tid < TPT) {
    int idx = loc0 + tid;
    int v = idx < cnt;
    int p = base + (v ? idx : 0);
    s_val[tid] = v;
    s_tok[tid] = a_tok[p];
    s_w[0][tid] = v ? a_w0[p] : 0.0f;
    s_w[1][tid] = v ? a_w1[p] : 0.0f;
  }
  __shared__ __align__(16) u16 As[TPT * 32];
  __shared__ __align__(16) u16 Bs[128 * 32];
  __shared__ __align__(16) u16 Hs[TPT * HS_STRIDE];
  __syncthreads();

  const int lrow = lane & 15, lk = (lane >> 4) * 8;

  // staging pointers (linear-in-tid => wave-uniform LDS base + lane*16 holds)
  const u16* encP = (tid < 64)
      ? Enc + (size_t)s_tok[tid >> 2] * DM + (tid & 3) * 8 : (const u16*)0;
  const int urow = tid >> 2;  // 0..63
  const u16* uP0 = Ub + ((size_t)pe0 * RK + urow) * DM + (tid & 3) * 8;
  const u16* uP1 = Ub + ((size_t)pe1 * RK + urow) * DM + (tid & 3) * 8;

  // ---- stage 1: [16 tok x 128], K = 1024 ----
  f32x4 acc1[2];
  acc1[0] = (f32x4){0.f, 0.f, 0.f, 0.f};
  acc1[1] = (f32x4){0.f, 0.f, 0.f, 0.f};

  for (int k0 = 0; k0 < DM; k0 += 32) {
    __syncthreads();
    if (tid < 64) gload_lds16(encP + k0, As + tid * 8);
    gload_lds16(uP0 + k0, Bs + tid * 8);
    gload_lds16(uP1 + k0, Bs + 2048 + tid * 8);
    __syncthreads();
    bf16x8 a  = *reinterpret_cast<const bf16x8*>(&As[lrow * 32 + lk]);
    bf16x8 b0 = *reinterpret_cast<const bf16x8*>(&Bs[(wave * 32 + lrow) * 32 + lk]);
    bf16x8 b1 = *reinterpret_cast<const bf16x8*>(&Bs[(wave * 32 + 16 + lrow) * 32 + lk]);
    acc1[0] = __builtin_amdgcn_mfma_f32_16x16x32_bf16(a, b0, acc1[0], 0, 0, 0);
    acc1[1] = __builtin_amdgcn_mfma_f32_16x16x32_bf16(a, b1, acc1[1], 0, 0, 0);
  }

  // silu * routing weight -> Hs ; wave w owns cols [w*32, w*32+32)
  {
    const int side = wave >> 1;
    #pragma unroll
    for (int cj = 0; cj < 2; ++cj)
      #pragma unroll
      for (int r = 0; r < 4; ++r) {
        int tok = (lane >> 4) * 4 + r;
        int col = wave * 32 + cj * 16 + lrow;
        float z = acc1[cj][r];
        float h = z / (1.0f + expf(-z)) * s_w[side][tok];
        Hs[tok * HS_STRIDE + col] = f2bf(h);
      }
  }
  __syncthreads();

  // ---- stage 2: wave owns 256 d-cols; K = 128 over H-cat ----
  const u16* V0 = Vb + (size_t)pe0 * DM * RK;
  const u16* V1 = Vb + (size_t)pe1 * DM * RK;
  const int d0w = wave * 256;

  f32x4 acc2[16];
  #pragma unroll
  for (int i = 0; i < 16; ++i) acc2[i] = (f32x4){0.f, 0.f, 0.f, 0.f};

  #pragma unroll
  for (int kk = 0; kk < 4; ++kk) {
    const u16* Vsel = (kk < 2) ? V0 : V1;
    const int kof = (kk & 1) * 32 + lk;
    bf16x8 hb = *reinterpret_cast<const bf16x8*>(&Hs[lrow * HS_STRIDE + kk * 32 + lk]);
    #pragma unroll
    for (int mi = 0; mi < 16; ++mi) {
      int d = d0w + mi * 16 + lrow;
      bf16x8 va = *reinterpret_cast<const bf16x8*>(Vsel + (size_t)d * RK + kof);
      acc2[mi] = __builtin_amdgcn_mfma_f32_16x16x32_bf16(va, hb, acc2[mi], 0, 0, 0);
    }
  }

  // epilogue: lane -> token (lane&15), 4 consecutive d; float4 stores
  const int tok = lane & 15;
  if (s_val[tok]) {
    const size_t trow = (size_t)s_tok[tok] * DM;
    #pragma unroll
    for (int mi = 0; mi < 16; ++mi) {
      int d = d0w + mi * 16 + (lane >> 4) * 4;
      size_t ro = trow + d;
      ushort4 ev = *reinterpret_cast<const ushort4*>(Enc + ro);
      float4 o;
      o.x = acc2[mi][0] + bf2f(ev.x);
      o.y = acc2[mi][1] + bf2f(ev.y);
      o.z = acc2[mi][2] + bf2f(ev.z);
      o.w = acc2[mi][3] + bf2f(ev.w);
      *reinterpret_cast<float4*>(Out + ro) = o;
    }
  }
}

// ---------------- host launch ----------------
extern "C" void kernel_launch(void* const* d_in, const int* in_sizes, int n_in,
                              void* d_out, int out_size, void* d_ws, size_t ws_size,
                              hipStream_t stream) {
  const float* x = (const float*)d_in[0];
  const float* We = (const float*)d_in[1];
  const float* be = (const float*)d_in[2];
  const float* Wg = (const float*)d_in[3];
  const float* U = (const float*)d_in[4];
  const float* V = (const float*)d_in[5];
  const float* gamma = (const float*)d_in[6];
  float* Out = (float*)d_out;

  char* ws = (char*)d_ws;
  size_t off = 0;
  auto alloc = [&](size_t bytes) -> void* {
    void* p = ws + off;
    off += (bytes + 255) & ~(size_t)255;
    return p;
  };
  u16* x_bf   = (u16*)alloc((size_t)B_TOK * DM * 2);
  u16* enc_bf = (u16*)alloc((size_t)B_TOK * DM * 2);
  u16* We_bf  = (u16*)alloc((size_t)DM * DM * 2);
  u16* U_bf   = (u16*)alloc((size_t)NEXP * RK * DM * 2);
  u16* V_bf   = (u16*)alloc((size_t)NEXP * DM * RK * 2);
  float* Wgeff = (float*)alloc((size_t)NEXP * DM * 4);
  float* gbias = (float*)alloc(NEXP * 4);
  int* tk_pid  = (int*)alloc((size_t)B_TOK * 4);
  float* tk_w0 = (float*)alloc((size_t)B_TOK * 4);
  float* tk_w1 = (float*)alloc((size_t)B_TOK * 4);
  int* counts  = (int*)alloc(NPAIR * 4);
  int* offsets = (int*)alloc((NPAIR + 1) * 4);
  int* cursors = (int*)alloc(NPAIR * 4);
  int* tile_pair = (int*)alloc(MAXTILE * 4);
  int* tile_loc  = (int*)alloc(MAXTILE * 4);
  int* n_tiles   = (int*)alloc(256);
  int* a_tok   = (int*)alloc((size_t)B_TOK * 4);
  float* a_w0  = (float*)alloc((size_t)B_TOK * 4);
  float* a_w1  = (float*)alloc((size_t)B_TOK * 4);
  (void)ws_size; (void)in_sizes; (void)n_in; (void)out_size;

  hipMemsetAsync(counts, 0, NPAIR * 4, stream);

  k_convert<<<256, 256, 0, stream>>>(We, We_bf, DM * DM / 4);
  k_convert<<<256, 256, 0, stream>>>(U, U_bf, NEXP * RK * DM / 4);
  k_convert<<<256, 256, 0, stream>>>(V, V_bf, NEXP * DM * RK / 4);
  k_wgeff<<<dim3(4, 16), 256, 0, stream>>>(Wg, We, be, Wgeff, gbias);
  k_gating<<<B_TOK / GT, 256, 0, stream>>>(x, x_bf, Wgeff, gbias, gamma,
                                           tk_pid, tk_w0, tk_w1, counts);
  k_scan<<<1, NPAIR, 0, stream>>>(counts, offsets, cursors, tile_pair, tile_loc, n_tiles);
  k_scatter<<<B_TOK / 256, 256, 0, stream>>>(tk_pid, tk_w0, tk_w1, cursors,
                                             a_tok, a_w0, a_w1);
  k_encoder<<<dim3(DM / 128, B_TOK / 128), 256, 0, stream>>>(x_bf, We_bf, be, enc_bf);
  k_expert<<<GRID_EXP, 256, 0, stream>>>(enc_bf, U_bf, V_bf, offsets, tile_pair, tile_loc,
                                         n_tiles, a_tok, a_w0, a_w1, Out);
}